// Round 10
// baseline (541.551 us; speedup 1.0000x reference)
//
#include <hip/hip_runtime.h>
#include <hip/hip_fp16.h>
#include <cstdint>

#define MB 8
#define TT 2048
#define DIMK 1024
#define CC 128
#define NG 32                 /* scan groups per batch, 4 rows each */
#define MROWS (MB*TT)         /* 16384 */
#define NPROJ 576
#define YSTR 576

using bf16x8 = __attribute__((__ext_vector_type__(8))) __bf16;
using f32x4v = __attribute__((__ext_vector_type__(4))) float;
using f32x2v = __attribute__((__ext_vector_type__(2))) float;

__device__ __forceinline__ unsigned short f2b(float f) {
    unsigned u = __float_as_uint(f);
    u += 0x7fffu + ((u >> 16) & 1u);
    return (unsigned short)(u >> 16);
}

// async global->LDS, 16B/lane, 1024B/instruction (used by the scan).
__device__ __forceinline__ void gload_lds16(const void* g, void* l) {
    __builtin_amdgcn_global_load_lds(
        (const __attribute__((address_space(1))) void*)g,
        (__attribute__((address_space(3))) void*)l, 16, 0, 0);
}

// ---------------------------------------------------------------------------
// Casts / packing  (R5 configuration: cast_x restored — the R9 fused f32-A
// proj GEMM re-read x 9x (one per N-tile) and was net negative)
// ---------------------------------------------------------------------------
__global__ __launch_bounds__(256) void cast_x_kernel(
    const float* __restrict__ in, unsigned short* __restrict__ outp)
{
    size_t i = ((size_t)blockIdx.x * 256 + threadIdx.x) * 8;
    float4 a = *(const float4*)(in + i);
    float4 b = *(const float4*)(in + i + 4);
    uint4 r;
    r.x = f2b(a.x) | ((unsigned)f2b(a.y) << 16);
    r.y = f2b(a.z) | ((unsigned)f2b(a.w) << 16);
    r.z = f2b(b.x) | ((unsigned)f2b(b.y) << 16);
    r.w = f2b(b.z) | ((unsigned)f2b(b.w) << 16);
    *(uint4*)(outp + i) = r;
}

// WcatT[n][k] bf16, n in [0,576): 0-127 Wq, ... 512 Wa, 513 Wb, rest 0.
__global__ __launch_bounds__(256) void pack_wt(
    const float* __restrict__ Wq, const float* __restrict__ Wk,
    const float* __restrict__ Wv, const float* __restrict__ Wg,
    const float* __restrict__ Wa, const float* __restrict__ Wb,
    unsigned short* __restrict__ WcatT)
{
    int idx = blockIdx.x * 256 + threadIdx.x;
    if (idx >= NPROJ * DIMK) return;
    int n = idx >> 10, k = idx & 1023;
    float v = 0.f;
    if      (n < 128) v = Wq[k * 128 + n];
    else if (n < 256) v = Wk[k * 128 + (n - 128)];
    else if (n < 384) v = Wv[k * 128 + (n - 256)];
    else if (n < 512) v = Wg[k * 128 + (n - 384)];
    else if (n == 512) v = Wa[k];
    else if (n == 513) v = Wb[k];
    WcatT[idx] = f2b(v);
}

__global__ void pack_bias(const float* __restrict__ bq, const float* __restrict__ bk,
                          const float* __restrict__ bv, const float* __restrict__ bg,
                          const float* __restrict__ ba, const float* __restrict__ bb,
                          float* __restrict__ biascat)
{
    int n = threadIdx.x;
    if (n >= NPROJ) return;
    float v = 0.f;
    if      (n < 128) v = bq[n];
    else if (n < 256) v = bk[n - 128];
    else if (n < 384) v = bv[n - 256];
    else if (n < 512) v = bg[n - 384];
    else if (n == 512) v = ba[0];
    else if (n == 513) v = bb[0];
    biascat[n] = v;
}

// WoT[n][k] bf16 (Wo is [CC][DIM])
__global__ __launch_bounds__(256) void cast_wot(
    const float* __restrict__ Wo, unsigned short* __restrict__ WoT)
{
    int idx = blockIdx.x * 256 + threadIdx.x;
    if (idx >= DIMK * CC) return;
    int n = idx >> 7, k = idx & 127;
    WoT[idx] = f2b(Wo[k * DIMK + n]);
}

// ---------------------------------------------------------------------------
// BF16 MFMA GEMM: C[M][N] = A[MxK bf16] @ BT[NxK bf16]^T + bias, fp32 out.
// R5-exact register-staged structure (verified best).
// ---------------------------------------------------------------------------
__global__ __launch_bounds__(256) void gemm_bt_bf16(
    const unsigned short* __restrict__ A, const unsigned short* __restrict__ BT,
    const float* __restrict__ bias, float* __restrict__ C,
    int M, int N, int K)
{
    __shared__ unsigned short As[4][128][8];   // [k-quad][m][j]
    __shared__ unsigned short Bs[4][64][8];    // [k-quad][n][j]
    int tid = threadIdx.x;
    int w = tid >> 6, l = tid & 63;
    int lm = l & 15, lq = l >> 4;
    int bm = blockIdx.y * 128, bn = blockIdx.x * 64;

    f32x4v acc[2][4];
#pragma unroll
    for (int rt = 0; rt < 2; rt++)
#pragma unroll
        for (int ct = 0; ct < 4; ct++) acc[rt][ct] = (f32x4v)(0.f);

    int ar = tid >> 1, ah = tid & 1;          // A stage: row ar, 16-elem half ah
    int brn = tid >> 2, bq = tid & 3;         // B stage: row brn, 8-elem quarter
    const unsigned short* Arow = A + (size_t)(bm + ar) * K + ah * 16;
    const unsigned short* Brow = BT + (size_t)(bn + brn) * K + bq * 8;

    for (int kk = 0; kk < K; kk += 32) {
        uint4 av0 = *(const uint4*)(Arow + kk);
        uint4 av1 = *(const uint4*)(Arow + kk + 8);
        uint4 bv  = *(const uint4*)(Brow + kk);
        __syncthreads();
        *(uint4*)&As[ah * 2][ar][0]     = av0;
        *(uint4*)&As[ah * 2 + 1][ar][0] = av1;
        *(uint4*)&Bs[bq][brn][0]        = bv;
        __syncthreads();
        bf16x8 af[2], bf[4];
#pragma unroll
        for (int rt = 0; rt < 2; rt++)
            __builtin_memcpy(&af[rt], &As[lq][w * 32 + rt * 16 + lm][0], 16);
#pragma unroll
        for (int ct = 0; ct < 4; ct++)
            __builtin_memcpy(&bf[ct], &Bs[lq][ct * 16 + lm][0], 16);
#pragma unroll
        for (int rt = 0; rt < 2; rt++)
#pragma unroll
            for (int ct = 0; ct < 4; ct++)
                acc[rt][ct] = __builtin_amdgcn_mfma_f32_16x16x32_bf16(
                    af[rt], bf[ct], acc[rt][ct], 0, 0, 0);
    }
#pragma unroll
    for (int rt = 0; rt < 2; rt++)
#pragma unroll
        for (int ct = 0; ct < 4; ct++) {
            int col = bn + ct * 16 + lm;
            float bcol = bias[col];
#pragma unroll
            for (int i = 0; i < 4; i++) {
                int row = bm + w * 32 + rt * 16 + lq * 4 + i;
                C[(size_t)row * N + col] = acc[rt][ct][i] + bcol;
            }
        }
}

// ---------------------------------------------------------------------------
// Post-projection (unchanged)
// ---------------------------------------------------------------------------
__global__ __launch_bounds__(64) void postproj_kernel(
    const float* __restrict__ Y, float* __restrict__ knorm,
    float* __restrict__ gbuf, float4* __restrict__ qvab)
{
    int m = blockIdx.x;
    int lane = threadIdx.x;
    int b = m >> 11, t = m & (TT - 1);
    const float* yr = Y + (size_t)m * YSTR;
    float k0 = yr[128 + lane], k1 = yr[192 + lane];
    float ss = k0 * k0 + k1 * k1;
#pragma unroll
    for (int mask = 1; mask < 64; mask <<= 1) ss += __shfl_xor(ss, mask);
    float inv = 1.0f / fmaxf(sqrtf(ss), 1e-12f);
    knorm[(size_t)m * CC + lane]      = k0 * inv;
    knorm[(size_t)m * CC + 64 + lane] = k1 * inv;
    float g0 = yr[384 + lane], g1 = yr[448 + lane];
    gbuf[(size_t)m * CC + lane]      = 1.f / (1.f + expf(-g0));
    gbuf[(size_t)m * CC + 64 + lane] = 1.f / (1.f + expf(-g1));
    float a  = 1.f / (1.f + expf(-yr[512]));
    float bb = 1.f / (1.f + expf(-yr[513]));
    {
        int i = lane;
        qvab[((size_t)(b * NG + (i >> 2)) * TT + t) * 4 + (i & 3)] =
            make_float4(yr[i], yr[256 + i], a, bb);
        i = lane + 64;
        qvab[((size_t)(b * NG + (i >> 2)) * TT + t) * 4 + (i & 3)] =
            make_float4(yr[i], yr[256 + i], a, bb);
    }
}

// ---------------------------------------------------------------------------
// Cross-lane helpers
// ---------------------------------------------------------------------------
__device__ __forceinline__ float dpp_add_xor1(float p) {
    int i = __builtin_amdgcn_mov_dpp(__float_as_int(p), 0xB1, 0xF, 0xF, true);
    return p + __int_as_float(i);
}
__device__ __forceinline__ float dpp_add_xor2(float p) {
    int i = __builtin_amdgcn_mov_dpp(__float_as_int(p), 0x4E, 0xF, 0xF, true);
    return p + __int_as_float(i);
}
__device__ __forceinline__ float dpp_add_mirror7(float p) {
    int i = __builtin_amdgcn_mov_dpp(__float_as_int(p), 0x141, 0xF, 0xF, true);
    return p + __int_as_float(i);
}
__device__ __forceinline__ float dpp_add_ror8(float p) {
    int i = __builtin_amdgcn_mov_dpp(__float_as_int(p), 0x128, 0xF, 0xF, true);
    return p + __int_as_float(i);
}
__device__ __forceinline__ int h2i(__half2 h) { int i; __builtin_memcpy(&i, &h, 4); return i; }
__device__ __forceinline__ __half2 i2h(int i) { __half2 h; __builtin_memcpy(&h, &i, 4); return h; }

// packed f32 helpers (lower to v_pk_mul_f32 / v_pk_fma_f32 on CDNA)
__device__ __forceinline__ f32x2v vfma2(f32x2v a, f32x2v b, f32x2v c) {
#if __has_builtin(__builtin_elementwise_fma)
    return __builtin_elementwise_fma(a, b, c);
#else
    return a * b + c;
#endif
}
__device__ __forceinline__ __half2 cvt2h(f32x2v v) {
    return __float22half2_rn(make_float2(v.x, v.y));
}

// gfx950 VALU-pipe cross-row swaps (no LDS pipe, no lgkmcnt).
__device__ __forceinline__ void pl16_swap(unsigned &a, unsigned &b) {
#if __has_builtin(__builtin_amdgcn_permlane16_swap)
    auto r = __builtin_amdgcn_permlane16_swap(a, b, false, false);
    a = (unsigned)r[0]; b = (unsigned)r[1];
#else
    asm volatile("v_permlane16_swap_b32 %0, %1" : "+v"(a), "+v"(b));
#endif
}
__device__ __forceinline__ void pl32_swap(unsigned &a, unsigned &b) {
#if __has_builtin(__builtin_amdgcn_permlane32_swap)
    auto r = __builtin_amdgcn_permlane32_swap(a, b, false, false);
    a = (unsigned)r[0]; b = (unsigned)r[1];
#else
    asm volatile("v_permlane32_swap_b32 %0, %1" : "+v"(a), "+v"(b));
#endif
}
// reduce helpers: p + p[lane^16], p + p[lane^32] (copy + swap + add)
__device__ __forceinline__ float pl16_add(float p) {
    unsigned a = __float_as_uint(p), b = a;
    pl16_swap(a, b);
    return __uint_as_float(a) + __uint_as_float(b);
}
__device__ __forceinline__ float pl32_add(float p) {
    unsigned a = __float_as_uint(p), b = a;
    pl32_swap(a, b);
    return __uint_as_float(a) + __uint_as_float(b);
}

// ---------------------------------------------------------------------------
// Sequential scan — R10: TWO ROWS (two independent chains) PER WAVE.
// R5's 4-wave version: 236 cy/step = ~97 issue + ~139 dependent-latency
// stall (the 16-op serial reduce chain can't be filled from one chain's own
// instructions). Co-residency can't help (total waves fixed by 1024 rows);
// the fix is ILP: each wave owns 2 of its group's 4 rows. The rows share k
// (one ds_read), have independent s-states, and the two reduce chains
// interleave in the issue stream -> per-row wall ~= half of one chain's
// stall-laden step. Per-row arithmetic bit-identical (same ops, same trees).
// Grid = MB*NG = 256 blocks x 128 threads (2 waves): wave w owns rows
// 2w, 2w+1. Staging: 9 gloads/wave/chunk (8 k + 1 q). COMBINE: 16
// slices/thread. Per-wave FIFO vmcnt: 9 (c<2), 25 steady, 16 last.
// ---------------------------------------------------------------------------
#define CH  32                 /* steps per chunk */
#define NCH (TT/CH)            /* 64 chunks */

template <bool ATOMIC>
__global__ __launch_bounds__(128, 1) void scan_kernel(
    const float* __restrict__ knorm, const float4* __restrict__ qvab,
    void* __restrict__ outp)
{
    __shared__ float lk[2 * CH * 128];        // 2 x 16 KiB k chunks
    __shared__ float lq[2 * CH * 16];         // 2 x 2 KiB qvab chunks
    __shared__ unsigned outb[2 * 4 * CH * 64]; // 2 x 32 KiB partial buffers

    int blk = blockIdx.x;
    int b = blk >> 5;
    int gi = blk & 31;
    int tid = threadIdx.x;
    int w = tid >> 6, lane = tid & 63;
    int ra = 2 * w, rb = 2 * w + 1;           // this wave's two rows
    f32x2v sA = (f32x2v)(0.f);
    f32x2v sB = (f32x2v)(0.f);
    size_t mbase = (size_t)b * TT;

    const char* kgb = (const char*)(knorm + mbase * CC);
    const char* qgb = (const char*)(qvab + (size_t)blk * TT * 4);
    size_t lane16 = (size_t)lane * 16;

#define STAGE_CHUNK(cc, bf) do {                                              \
    char* lkd = (char*)lk + (size_t)(bf) * (CH * 512) + (size_t)w * 8192;     \
    const char* kc_ = kgb + (size_t)(cc) * (CH * 512) + (size_t)w * 8192;     \
    _Pragma("unroll")                                                         \
    for (int i_ = 0; i_ < 8; ++i_)                                            \
        gload_lds16(kc_ + (size_t)i_ * 1024 + lane16, lkd + i_ * 1024);       \
    {                                                                         \
        char* lqd = (char*)lq + (size_t)(bf) * (CH * 64) + (size_t)w * 1024;  \
        const char* qc_ = qgb + (size_t)(cc) * (CH * 64) + (size_t)w * 1024;  \
        gload_lds16(qc_ + lane16, lqd);                                       \
    }                                                                         \
} while (0)

#define LDK(st, sl) do {                                                      \
    kP[sl] = *(const f32x2v*)(lkc + (st) * 128 + lane * 2);                   \
    qPa[sl] = *(const f32x4v*)(lqc + (st) * 16 + ra * 4);                     \
    qPb[sl] = *(const f32x4v*)(lqc + (st) * 16 + rb * 4);                     \
} while (0)

// one step of BOTH rows: two independent chains, interleaved by the
// scheduler. Per-row arithmetic identical to the R5 KSTEP.
#define KSTEP2(st, sl) do {                                                   \
    f32x2v k2 = kP[sl];                                                       \
    f32x4v qa = qPa[sl];                                                      \
    f32x4v qb = qPb[sl];                                                      \
    f32x2v psa = sA * k2;                                                     \
    f32x2v psb = sB * k2;                                                     \
    float pa = psa[0] + psa[1];                                               \
    float pb = psb[0] + psb[1];                                               \
    pa = dpp_add_xor1(pa);    pb = dpp_add_xor1(pb);                          \
    pa = dpp_add_xor2(pa);    pb = dpp_add_xor2(pb);                          \
    pa = dpp_add_mirror7(pa); pb = dpp_add_mirror7(pb);                       \
    pa = dpp_add_ror8(pa);    pb = dpp_add_ror8(pb);                          \
    pa = pl16_add(pa);        pb = pl16_add(pb);                              \
    pa = pl32_add(pa);        pb = pl32_add(pb);                              \
    float baA = qa[2] * qa[3], bvA = qa[3] * qa[1];                           \
    float baB = qb[2] * qb[3], bvB = qb[3] * qb[1];                           \
    float crA = fmaf(-baA, pa, bvA);                                          \
    float crB = fmaf(-baB, pb, bvB);                                          \
    f32x2v atA = {qa[2], qa[2]}, crA2 = {crA, crA}, q2A = {qa[0], qa[0]};     \
    f32x2v atB = {qb[2], qb[2]}, crB2 = {crB, crB}, q2B = {qb[0], qb[0]};     \
    sA = vfma2(k2, crA2, sA * atA);                                           \
    sB = vfma2(k2, crB2, sB * atB);                                           \
    __half2 pbA = cvt2h(q2A * sA);                                            \
    __half2 pbB = cvt2h(q2B * sB);                                            \
    obwA[(st) * 64] = (unsigned)h2i(pbA);                                     \
    obwB[(st) * 64] = (unsigned)h2i(pbB);                                     \
} while (0)

#define COMBINE(cc) do {                                                      \
    const unsigned* ob_ = outb + (size_t)((cc) & 1) * (4 * CH * 64);          \
    int tg_ = (cc) * CH;                                                      \
    _Pragma("unroll")                                                         \
    for (int j_ = 0; j_ < 16; ++j_) {                                         \
        int slot_ = tid + 128 * j_;                                           \
        int st_ = slot_ >> 6, ln_ = slot_ & 63;                               \
        __half2 h0_ = i2h((int)ob_[(0 * CH + st_) * 64 + ln_]);               \
        __half2 h1_ = i2h((int)ob_[(1 * CH + st_) * 64 + ln_]);               \
        __half2 h2_ = i2h((int)ob_[(2 * CH + st_) * 64 + ln_]);               \
        __half2 h3_ = i2h((int)ob_[(3 * CH + st_) * 64 + ln_]);               \
        __half2 r_ = __hadd2(__hadd2(h0_, h1_), __hadd2(h2_, h3_));           \
        size_t m_ = mbase + tg_ + st_;                                        \
        if (ATOMIC) {                                                         \
            float2 f_ = __half22float2(r_);                                   \
            float* op_ = (float*)outp + m_ * CC + ln_ * 2;                    \
            atomicAdd(op_, f_.x);                                             \
            atomicAdd(op_ + 1, f_.y);                                         \
        } else {                                                              \
            ((unsigned*)outp)[((size_t)gi * MROWS + m_) * 64 + ln_] =         \
                (unsigned)h2i(r_);                                            \
        }                                                                     \
    }                                                                         \
} while (0)

    STAGE_CHUNK(0, 0);

    for (int c = 0; c < NCH; ++c) {
        int cur = c & 1;
        if (c + 1 < NCH) STAGE_CHUNK(c + 1, cur ^ 1);
        // per-wave FIFO (9 loads/chunk, 16 stores/COMBINE):
        //  c<2: only loads outstanding -> 9
        //  steady: stores(16 from COMBINE(c-2)) + S(c+1)(9) newer than S(c)
        //  last: no S(c+1) -> 16
        if (c < 2) {
            asm volatile("s_waitcnt vmcnt(9)" ::: "memory");
        } else if (c + 1 < NCH) {
            asm volatile("s_waitcnt vmcnt(25)" ::: "memory");
        } else {
            asm volatile("s_waitcnt vmcnt(16)" ::: "memory");
        }
        asm volatile("s_waitcnt lgkmcnt(0)" ::: "memory");
        __builtin_amdgcn_s_barrier();
        if (c > 0) COMBINE(c - 1);

        const float* lkc = lk + (size_t)cur * CH * 128;
        const float* lqc = lq + (size_t)cur * CH * 16;
        unsigned* obwA = outb + (size_t)(cur * 4 + ra) * CH * 64 + lane;
        unsigned* obwB = outb + (size_t)(cur * 4 + rb) * CH * 64 + lane;

        f32x2v kP[4];
        f32x4v qPa[4], qPb[4];
        LDK(0, 0); LDK(1, 1); LDK(2, 2);
#pragma unroll
        for (int st = 0; st < CH; ++st) {
            if (st + 3 < CH) LDK(st + 3, (st + 3) & 3);
            KSTEP2(st, st & 3);
        }
    }
    asm volatile("s_waitcnt lgkmcnt(0)" ::: "memory");
    __builtin_amdgcn_s_barrier();
    COMBINE(NCH - 1);
#undef STAGE_CHUNK
#undef LDK
#undef KSTEP2
#undef COMBINE
}

// ---------------------------------------------------------------------------
// Combine f16x2 partials over NG groups, apply gate, emit bf16 pair.
// ---------------------------------------------------------------------------
__global__ __launch_bounds__(256) void combine_kernel(
    const unsigned* __restrict__ opart,
    const float* __restrict__ gbuf, unsigned* __restrict__ ocombb)
{
    size_t idx = (size_t)blockIdx.x * 256 + threadIdx.x;  // < MROWS*64
    float sx = 0.f, sy = 0.f;
#pragma unroll
    for (int gi = 0; gi < NG; ++gi) {
        __half2 h = i2h((int)opart[(size_t)gi * MROWS * 64 + idx]);
        float2 f = __half22float2(h);
        sx += f.x; sy += f.y;
    }
    float2 g = *(const float2*)(gbuf + idx * 2);
    ocombb[idx] = f2b(sx * g.x) | ((unsigned)f2b(sy * g.y) << 16);
}

__global__ __launch_bounds__(256) void gate_kernel(
    const float* __restrict__ ocombf, const float* __restrict__ gbuf,
    unsigned short* __restrict__ ocombb)
{
    size_t idx = (size_t)blockIdx.x * 256 + threadIdx.x;  // < MROWS*CC
    ocombb[idx] = f2b(ocombf[idx] * gbuf[idx]);
}

// ---------------------------------------------------------------------------
extern "C" void kernel_launch(void* const* d_in, const int* in_sizes, int n_in,
                              void* d_out, int out_size, void* d_ws, size_t ws_size,
                              hipStream_t stream)
{
    const float* x  = (const float*)d_in[0];
    const float* Wq = (const float*)d_in[1];
    const float* bq = (const float*)d_in[2];
    const float* Wk = (const float*)d_in[3];
    const float* bk = (const float*)d_in[4];
    const float* Wv = (const float*)d_in[5];
    const float* bv = (const float*)d_in[6];
    const float* Wa = (const float*)d_in[7];
    const float* ba = (const float*)d_in[8];
    const float* Wb = (const float*)d_in[9];
    const float* bb = (const float*)d_in[10];
    const float* Wg = (const float*)d_in[11];
    const float* bg = (const float*)d_in[12];
    const float* Wo = (const float*)d_in[13];
    const float* bo = (const float*)d_in[14];
    float* out = (float*)d_out;

    // ---- workspace layout (floats), with aliasing:
    //  qvab aliases xb (xb dead after proj GEMM; qvab written by postproj)
    //  opart aliases Y and beyond (Y dead after postproj)
    //  ocombf (atomic fallback) aliases opart
    float* ws = (float*)d_ws;
    size_t off = 0;
    float* knorm   = ws + off; off += (size_t)MROWS * CC;        // 2.10M
    float* gbuf    = ws + off; off += (size_t)MROWS * CC;        // 2.10M
    unsigned* ocombb = (unsigned*)(ws + off); off += (size_t)MROWS * CC / 2;
    unsigned short* WcatT = (unsigned short*)(ws + off); off += (size_t)NPROJ * DIMK / 2;
    unsigned short* WoT   = (unsigned short*)(ws + off); off += (size_t)DIMK * CC / 2;
    float* biascat = ws + off; off += NPROJ;
    unsigned short* xb = (unsigned short*)(ws + off);
    float* qvab    = ws + off; off += (size_t)MROWS * DIMK / 2;  // 8.39M (both)
    float* Y       = ws + off;
    size_t opart_off = off;
    off += (size_t)MROWS * YSTR;                                  // Y end
    float* ocombf  = ws + opart_off;
    unsigned* opart = (unsigned*)(ws + opart_off);
    size_t opart_end = opart_off + (size_t)NG * MROWS * 64;
    size_t need_big = (opart_end > off ? opart_end : off) * sizeof(float);
    bool big = ws_size >= need_big;

    hipLaunchKernelGGL(cast_x_kernel, dim3((size_t)MROWS * DIMK / 8 / 256), dim3(256), 0, stream,
                       x, xb);
    hipLaunchKernelGGL(pack_wt, dim3(NPROJ * DIMK / 256), dim3(256), 0, stream,
                       Wq, Wk, Wv, Wg, Wa, Wb, WcatT);
    hipLaunchKernelGGL(pack_bias, dim3(1), dim3(NPROJ), 0, stream,
                       bq, bk, bv, bg, ba, bb, biascat);
    hipLaunchKernelGGL(cast_wot, dim3(DIMK * CC / 256), dim3(256), 0, stream,
                       Wo, WoT);
    // projection GEMM: Y[16384][576] = xb @ WcatT^T + biascat
    hipLaunchKernelGGL(gemm_bt_bf16, dim3(NPROJ / 64, MROWS / 128), dim3(256), 0, stream,
                       xb, WcatT, biascat, Y, MROWS, NPROJ, DIMK);
    hipLaunchKernelGGL(postproj_kernel, dim3(MROWS), dim3(64), 0, stream,
                       Y, knorm, gbuf, (float4*)qvab);
    if (big) {
        hipLaunchKernelGGL((scan_kernel<false>), dim3(MB * NG), dim3(128), 0, stream,
                           knorm, (const float4*)qvab, (void*)opart);
        hipLaunchKernelGGL(combine_kernel, dim3(MROWS * 64 / 256), dim3(256), 0, stream,
                           opart, gbuf, ocombb);
    } else {
        (void)hipMemsetAsync(ocombf, 0, (size_t)MROWS * CC * sizeof(float), stream);
        hipLaunchKernelGGL((scan_kernel<true>), dim3(MB * NG), dim3(128), 0, stream,
                           knorm, (const float4*)qvab, (void*)ocombf);
        hipLaunchKernelGGL(gate_kernel, dim3(MROWS * CC / 256), dim3(256), 0, stream,
                           ocombf, gbuf, (unsigned short*)ocombb);
    }
    // output GEMM: out[16384][1024] = ocombb @ WoT^T + bo
    hipLaunchKernelGGL(gemm_bt_bf16, dim3(DIMK / 64, MROWS / 128), dim3(256), 0, stream,
                       (const unsigned short*)ocombb, WoT, bo, out, MROWS, DIMK, CC);
}

// Round 11
// 467.407 us; speedup vs baseline: 1.1586x; 1.1586x over previous
//
#include <hip/hip_runtime.h>
#include <hip/hip_fp16.h>
#include <cstdint>

#define MB 8
#define TT 2048
#define DIMK 1024
#define CC 128
#define NG 32                 /* scan groups per batch, 4 rows each */
#define MROWS (MB*TT)         /* 16384 */
#define NPROJ 576
#define YSTR 576

using bf16x8 = __attribute__((__ext_vector_type__(8))) __bf16;
using f32x4v = __attribute__((__ext_vector_type__(4))) float;
using f32x2v = __attribute__((__ext_vector_type__(2))) float;

__device__ __forceinline__ unsigned short f2b(float f) {
    unsigned u = __float_as_uint(f);
    u += 0x7fffu + ((u >> 16) & 1u);
    return (unsigned short)(u >> 16);
}

// async global->LDS, 16B/lane, 1024B/instruction (used by the scan).
__device__ __forceinline__ void gload_lds16(const void* g, void* l) {
    __builtin_amdgcn_global_load_lds(
        (const __attribute__((address_space(1))) void*)g,
        (__attribute__((address_space(3))) void*)l, 16, 0, 0);
}

// ---------------------------------------------------------------------------
// Casts / packing (R5 configuration — verified best non-scan)
// ---------------------------------------------------------------------------
__global__ __launch_bounds__(256) void cast_x_kernel(
    const float* __restrict__ in, unsigned short* __restrict__ outp)
{
    size_t i = ((size_t)blockIdx.x * 256 + threadIdx.x) * 8;
    float4 a = *(const float4*)(in + i);
    float4 b = *(const float4*)(in + i + 4);
    uint4 r;
    r.x = f2b(a.x) | ((unsigned)f2b(a.y) << 16);
    r.y = f2b(a.z) | ((unsigned)f2b(a.w) << 16);
    r.z = f2b(b.x) | ((unsigned)f2b(b.y) << 16);
    r.w = f2b(b.z) | ((unsigned)f2b(b.w) << 16);
    *(uint4*)(outp + i) = r;
}

// WcatT[n][k] bf16, n in [0,576): 0-127 Wq, ... 512 Wa, 513 Wb, rest 0.
__global__ __launch_bounds__(256) void pack_wt(
    const float* __restrict__ Wq, const float* __restrict__ Wk,
    const float* __restrict__ Wv, const float* __restrict__ Wg,
    const float* __restrict__ Wa, const float* __restrict__ Wb,
    unsigned short* __restrict__ WcatT)
{
    int idx = blockIdx.x * 256 + threadIdx.x;
    if (idx >= NPROJ * DIMK) return;
    int n = idx >> 10, k = idx & 1023;
    float v = 0.f;
    if      (n < 128) v = Wq[k * 128 + n];
    else if (n < 256) v = Wk[k * 128 + (n - 128)];
    else if (n < 384) v = Wv[k * 128 + (n - 256)];
    else if (n < 512) v = Wg[k * 128 + (n - 384)];
    else if (n == 512) v = Wa[k];
    else if (n == 513) v = Wb[k];
    WcatT[idx] = f2b(v);
}

__global__ void pack_bias(const float* __restrict__ bq, const float* __restrict__ bk,
                          const float* __restrict__ bv, const float* __restrict__ bg,
                          const float* __restrict__ ba, const float* __restrict__ bb,
                          float* __restrict__ biascat)
{
    int n = threadIdx.x;
    if (n >= NPROJ) return;
    float v = 0.f;
    if      (n < 128) v = bq[n];
    else if (n < 256) v = bk[n - 128];
    else if (n < 384) v = bv[n - 256];
    else if (n < 512) v = bg[n - 384];
    else if (n == 512) v = ba[0];
    else if (n == 513) v = bb[0];
    biascat[n] = v;
}

// WoT[n][k] bf16 (Wo is [CC][DIM])
__global__ __launch_bounds__(256) void cast_wot(
    const float* __restrict__ Wo, unsigned short* __restrict__ WoT)
{
    int idx = blockIdx.x * 256 + threadIdx.x;
    if (idx >= DIMK * CC) return;
    int n = idx >> 7, k = idx & 127;
    WoT[idx] = f2b(Wo[k * DIMK + n]);
}

// ---------------------------------------------------------------------------
// BF16 MFMA GEMM: C[M][N] = A[MxK bf16] @ BT[NxK bf16]^T + bias, fp32 out.
// R5-exact register-staged structure (verified best).
// ---------------------------------------------------------------------------
__global__ __launch_bounds__(256) void gemm_bt_bf16(
    const unsigned short* __restrict__ A, const unsigned short* __restrict__ BT,
    const float* __restrict__ bias, float* __restrict__ C,
    int M, int N, int K)
{
    __shared__ unsigned short As[4][128][8];   // [k-quad][m][j]
    __shared__ unsigned short Bs[4][64][8];    // [k-quad][n][j]
    int tid = threadIdx.x;
    int w = tid >> 6, l = tid & 63;
    int lm = l & 15, lq = l >> 4;
    int bm = blockIdx.y * 128, bn = blockIdx.x * 64;

    f32x4v acc[2][4];
#pragma unroll
    for (int rt = 0; rt < 2; rt++)
#pragma unroll
        for (int ct = 0; ct < 4; ct++) acc[rt][ct] = (f32x4v)(0.f);

    int ar = tid >> 1, ah = tid & 1;          // A stage: row ar, 16-elem half ah
    int brn = tid >> 2, bq = tid & 3;         // B stage: row brn, 8-elem quarter
    const unsigned short* Arow = A + (size_t)(bm + ar) * K + ah * 16;
    const unsigned short* Brow = BT + (size_t)(bn + brn) * K + bq * 8;

    for (int kk = 0; kk < K; kk += 32) {
        uint4 av0 = *(const uint4*)(Arow + kk);
        uint4 av1 = *(const uint4*)(Arow + kk + 8);
        uint4 bv  = *(const uint4*)(Brow + kk);
        __syncthreads();
        *(uint4*)&As[ah * 2][ar][0]     = av0;
        *(uint4*)&As[ah * 2 + 1][ar][0] = av1;
        *(uint4*)&Bs[bq][brn][0]        = bv;
        __syncthreads();
        bf16x8 af[2], bf[4];
#pragma unroll
        for (int rt = 0; rt < 2; rt++)
            __builtin_memcpy(&af[rt], &As[lq][w * 32 + rt * 16 + lm][0], 16);
#pragma unroll
        for (int ct = 0; ct < 4; ct++)
            __builtin_memcpy(&bf[ct], &Bs[lq][ct * 16 + lm][0], 16);
#pragma unroll
        for (int rt = 0; rt < 2; rt++)
#pragma unroll
            for (int ct = 0; ct < 4; ct++)
                acc[rt][ct] = __builtin_amdgcn_mfma_f32_16x16x32_bf16(
                    af[rt], bf[ct], acc[rt][ct], 0, 0, 0);
    }
#pragma unroll
    for (int rt = 0; rt < 2; rt++)
#pragma unroll
        for (int ct = 0; ct < 4; ct++) {
            int col = bn + ct * 16 + lm;
            float bcol = bias[col];
#pragma unroll
            for (int i = 0; i < 4; i++) {
                int row = bm + w * 32 + rt * 16 + lq * 4 + i;
                C[(size_t)row * N + col] = acc[rt][ct][i] + bcol;
            }
        }
}

// ---------------------------------------------------------------------------
// Post-projection (unchanged)
// ---------------------------------------------------------------------------
__global__ __launch_bounds__(64) void postproj_kernel(
    const float* __restrict__ Y, float* __restrict__ knorm,
    float* __restrict__ gbuf, float4* __restrict__ qvab)
{
    int m = blockIdx.x;
    int lane = threadIdx.x;
    int b = m >> 11, t = m & (TT - 1);
    const float* yr = Y + (size_t)m * YSTR;
    float k0 = yr[128 + lane], k1 = yr[192 + lane];
    float ss = k0 * k0 + k1 * k1;
#pragma unroll
    for (int mask = 1; mask < 64; mask <<= 1) ss += __shfl_xor(ss, mask);
    float inv = 1.0f / fmaxf(sqrtf(ss), 1e-12f);
    knorm[(size_t)m * CC + lane]      = k0 * inv;
    knorm[(size_t)m * CC + 64 + lane] = k1 * inv;
    float g0 = yr[384 + lane], g1 = yr[448 + lane];
    gbuf[(size_t)m * CC + lane]      = 1.f / (1.f + expf(-g0));
    gbuf[(size_t)m * CC + 64 + lane] = 1.f / (1.f + expf(-g1));
    float a  = 1.f / (1.f + expf(-yr[512]));
    float bb = 1.f / (1.f + expf(-yr[513]));
    {
        int i = lane;
        qvab[((size_t)(b * NG + (i >> 2)) * TT + t) * 4 + (i & 3)] =
            make_float4(yr[i], yr[256 + i], a, bb);
        i = lane + 64;
        qvab[((size_t)(b * NG + (i >> 2)) * TT + t) * 4 + (i & 3)] =
            make_float4(yr[i], yr[256 + i], a, bb);
    }
}

// ---------------------------------------------------------------------------
// Cross-lane helpers
// ---------------------------------------------------------------------------
__device__ __forceinline__ float dpp_add_xor1(float p) {
    int i = __builtin_amdgcn_mov_dpp(__float_as_int(p), 0xB1, 0xF, 0xF, true);
    return p + __int_as_float(i);
}
__device__ __forceinline__ float dpp_add_xor2(float p) {
    int i = __builtin_amdgcn_mov_dpp(__float_as_int(p), 0x4E, 0xF, 0xF, true);
    return p + __int_as_float(i);
}
__device__ __forceinline__ float dpp_add_mirror7(float p) {
    int i = __builtin_amdgcn_mov_dpp(__float_as_int(p), 0x141, 0xF, 0xF, true);
    return p + __int_as_float(i);
}
__device__ __forceinline__ float dpp_add_ror8(float p) {
    int i = __builtin_amdgcn_mov_dpp(__float_as_int(p), 0x128, 0xF, 0xF, true);
    return p + __int_as_float(i);
}
__device__ __forceinline__ int h2i(__half2 h) { int i; __builtin_memcpy(&i, &h, 4); return i; }
__device__ __forceinline__ __half2 i2h(int i) { __half2 h; __builtin_memcpy(&h, &i, 4); return h; }

// packed f32 helpers (lower to v_pk_mul_f32 / v_pk_fma_f32 on CDNA)
__device__ __forceinline__ f32x2v vfma2(f32x2v a, f32x2v b, f32x2v c) {
#if __has_builtin(__builtin_elementwise_fma)
    return __builtin_elementwise_fma(a, b, c);
#else
    return a * b + c;
#endif
}
__device__ __forceinline__ __half2 cvt2h(f32x2v v) {
    return __float22half2_rn(make_float2(v.x, v.y));
}

// gfx950 VALU-pipe cross-row swaps (no LDS pipe, no lgkmcnt).
__device__ __forceinline__ void pl16_swap(unsigned &a, unsigned &b) {
#if __has_builtin(__builtin_amdgcn_permlane16_swap)
    auto r = __builtin_amdgcn_permlane16_swap(a, b, false, false);
    a = (unsigned)r[0]; b = (unsigned)r[1];
#else
    asm volatile("v_permlane16_swap_b32 %0, %1" : "+v"(a), "+v"(b));
#endif
}
// p + p[lane^16] (verified bit-exact in R2..R9 usage)
__device__ __forceinline__ float pl16_add(float p) {
    unsigned a = __float_as_uint(p), b = a;
    pl16_swap(a, b);
    return __uint_as_float(a) + __uint_as_float(b);
}

// ---------------------------------------------------------------------------
// Sequential scan — R11: HALF-WAVE ROW SPLIT (2 rows/wave, shared reduce).
// R10's failure: duplicating the whole step per row doubled the issue
// stream (~220cy) — ILP must SHARE instructions, not duplicate them.
// Here lanes 0-31 own row 2w (4 cols/lane), lanes 32-63 own row 2w+1.
// All reduce stages operate within 16-lane rows (DPP) or within 32-lane
// halves (pl16), so ONE 5-stage sequence (4 DPP + pl16; pl32 dropped)
// reduces BOTH rows simultaneously. k ds_read broadcasts across halves.
// Per-wave issue ~= R5's single-row step, but 2 rows retire per step.
// Grid = MB*NG = 256 blocks x 128 threads (2 waves).
// Per-row dot = 32 lanes x 4 cols (fp32 add reorder vs R5; output still
// dominated by f16 rounding -> absmax ~unchanged).
// Staging: 9 gloads/wave/chunk (8 k + 1 q). COMBINE: 16 slices/thread.
// Per-wave FIFO vmcnt: 9 (c<2), 25 steady, 16 last (derivation in R10).
// ---------------------------------------------------------------------------
#define CH  32                 /* steps per chunk */
#define NCH (TT/CH)            /* 64 chunks */

template <bool ATOMIC>
__global__ __launch_bounds__(128, 1) void scan_kernel(
    const float* __restrict__ knorm, const float4* __restrict__ qvab,
    void* __restrict__ outp)
{
    __shared__ float lk[2 * CH * 128];        // 2 x 16 KiB k chunks
    __shared__ float lq[2 * CH * 16];         // 2 x 2 KiB qvab chunks
    __shared__ unsigned outb[2 * 4 * CH * 64]; // 2 x 32 KiB partial buffers

    int blk = blockIdx.x;
    int b = blk >> 5;
    int gi = blk & 31;
    int tid = threadIdx.x;
    int w = tid >> 6, lane = tid & 63;
    int half = lane >> 5;            // 0: row 2w, 1: row 2w+1
    int row = 2 * w + half;
    int cl = lane & 31;              // column-lane: cols cl*4 .. cl*4+3
    f32x2v s0 = (f32x2v)(0.f);       // cols cl*4, cl*4+1
    f32x2v s1 = (f32x2v)(0.f);       // cols cl*4+2, cl*4+3
    size_t mbase = (size_t)b * TT;

    const char* kgb = (const char*)(knorm + mbase * CC);
    const char* qgb = (const char*)(qvab + (size_t)blk * TT * 4);
    size_t lane16 = (size_t)lane * 16;

#define STAGE_CHUNK(cc, bf) do {                                              \
    char* lkd = (char*)lk + (size_t)(bf) * (CH * 512) + (size_t)w * 8192;     \
    const char* kc_ = kgb + (size_t)(cc) * (CH * 512) + (size_t)w * 8192;     \
    _Pragma("unroll")                                                         \
    for (int i_ = 0; i_ < 8; ++i_)                                            \
        gload_lds16(kc_ + (size_t)i_ * 1024 + lane16, lkd + i_ * 1024);       \
    {                                                                         \
        char* lqd = (char*)lq + (size_t)(bf) * (CH * 64) + (size_t)w * 1024;  \
        const char* qc_ = qgb + (size_t)(cc) * (CH * 64) + (size_t)w * 1024;  \
        gload_lds16(qc_ + lane16, lqd);                                       \
    }                                                                         \
} while (0)

#define LDK(st, sl) do {                                                      \
    kP[sl] = *(const f32x4v*)(lkc + (st) * 128 + cl * 4);                     \
    qP[sl] = *(const f32x4v*)(lqc + (st) * 16 + row * 4);                     \
} while (0)

// one step of BOTH rows; the reduce instructions are shared (each 32-half
// carries its own row's partials through the same DPP/pl16 sequence).
#define KSTEP(st, sl) do {                                                    \
    f32x4v k4 = kP[sl];                                                       \
    f32x4v qv = qP[sl];                                                       \
    f32x2v k20 = __builtin_shufflevector(k4, k4, 0, 1);                       \
    f32x2v k21 = __builtin_shufflevector(k4, k4, 2, 3);                       \
    f32x2v ps0 = s0 * k20;                                                    \
    f32x2v ps1 = s1 * k21;                                                    \
    f32x2v pss = ps0 + ps1;                                                   \
    float p_ = pss[0] + pss[1];                                               \
    p_ = dpp_add_xor1(p_);                                                    \
    p_ = dpp_add_xor2(p_);                                                    \
    p_ = dpp_add_mirror7(p_);                                                 \
    p_ = dpp_add_ror8(p_);   /* 16-lane row sum */                            \
    p_ = pl16_add(p_);       /* 32-lane half sum = this row's full dot */     \
    float q_ = qv[0], v_ = qv[1], at_ = qv[2], bt_ = qv[3];                   \
    float ba_ = at_ * bt_, bv_ = bt_ * v_;                                    \
    float cr_ = fmaf(-ba_, p_, bv_);                                          \
    f32x2v at2_ = {at_, at_};                                                 \
    f32x2v cr2_ = {cr_, cr_};                                                 \
    f32x2v q2_  = {q_, q_};                                                   \
    s0 = vfma2(k20, cr2_, s0 * at2_);                                         \
    s1 = vfma2(k21, cr2_, s1 * at2_);                                         \
    __half2 o0_ = cvt2h(q2_ * s0);                                            \
    __half2 o1_ = cvt2h(q2_ * s1);                                            \
    *(uint2*)(obw + (st) * 64) =                                              \
        make_uint2((unsigned)h2i(o0_), (unsigned)h2i(o1_));                   \
} while (0)

#define COMBINE(cc) do {                                                      \
    const unsigned* ob_ = outb + (size_t)((cc) & 1) * (4 * CH * 64);          \
    int tg_ = (cc) * CH;                                                      \
    _Pragma("unroll")                                                         \
    for (int j_ = 0; j_ < 16; ++j_) {                                         \
        int slot_ = tid + 128 * j_;                                           \
        int st_ = slot_ >> 6, ln_ = slot_ & 63;                               \
        __half2 h0_ = i2h((int)ob_[(0 * CH + st_) * 64 + ln_]);               \
        __half2 h1_ = i2h((int)ob_[(1 * CH + st_) * 64 + ln_]);               \
        __half2 h2_ = i2h((int)ob_[(2 * CH + st_) * 64 + ln_]);               \
        __half2 h3_ = i2h((int)ob_[(3 * CH + st_) * 64 + ln_]);               \
        __half2 r_ = __hadd2(__hadd2(h0_, h1_), __hadd2(h2_, h3_));           \
        size_t m_ = mbase + tg_ + st_;                                        \
        if (ATOMIC) {                                                         \
            float2 f_ = __half22float2(r_);                                   \
            float* op_ = (float*)outp + m_ * CC + ln_ * 2;                    \
            atomicAdd(op_, f_.x);                                             \
            atomicAdd(op_ + 1, f_.y);                                         \
        } else {                                                              \
            ((unsigned*)outp)[((size_t)gi * MROWS + m_) * 64 + ln_] =         \
                (unsigned)h2i(r_);                                            \
        }                                                                     \
    }                                                                         \
} while (0)

    STAGE_CHUNK(0, 0);

    for (int c = 0; c < NCH; ++c) {
        int cur = c & 1;
        if (c + 1 < NCH) STAGE_CHUNK(c + 1, cur ^ 1);
        // per-wave FIFO (9 loads/chunk, 16 stores/COMBINE):
        if (c < 2) {
            asm volatile("s_waitcnt vmcnt(9)" ::: "memory");
        } else if (c + 1 < NCH) {
            asm volatile("s_waitcnt vmcnt(25)" ::: "memory");
        } else {
            asm volatile("s_waitcnt vmcnt(16)" ::: "memory");
        }
        asm volatile("s_waitcnt lgkmcnt(0)" ::: "memory");
        __builtin_amdgcn_s_barrier();
        if (c > 0) COMBINE(c - 1);

        const float* lkc = lk + (size_t)cur * CH * 128;
        const float* lqc = lq + (size_t)cur * CH * 16;
        // this half-wave's output row: word pair (cl*2, cl*2+1) of 64
        unsigned* obw = outb + (size_t)(cur * 4 + row) * CH * 64 + cl * 2;

        f32x4v kP[4];
        f32x4v qP[4];
        LDK(0, 0); LDK(1, 1); LDK(2, 2);
#pragma unroll
        for (int st = 0; st < CH; ++st) {
            if (st + 3 < CH) LDK(st + 3, (st + 3) & 3);
            KSTEP(st, st & 3);
        }
    }
    asm volatile("s_waitcnt lgkmcnt(0)" ::: "memory");
    __builtin_amdgcn_s_barrier();
    COMBINE(NCH - 1);
#undef STAGE_CHUNK
#undef LDK
#undef KSTEP
#undef COMBINE
}

// ---------------------------------------------------------------------------
// Combine f16x2 partials over NG groups, apply gate, emit bf16 pair.
// ---------------------------------------------------------------------------
__global__ __launch_bounds__(256) void combine_kernel(
    const unsigned* __restrict__ opart,
    const float* __restrict__ gbuf, unsigned* __restrict__ ocombb)
{
    size_t idx = (size_t)blockIdx.x * 256 + threadIdx.x;  // < MROWS*64
    float sx = 0.f, sy = 0.f;
#pragma unroll
    for (int gi = 0; gi < NG; ++gi) {
        __half2 h = i2h((int)opart[(size_t)gi * MROWS * 64 + idx]);
        float2 f = __half22float2(h);
        sx += f.x; sy += f.y;
    }
    float2 g = *(const float2*)(gbuf + idx * 2);
    ocombb[idx] = f2b(sx * g.x) | ((unsigned)f2b(sy * g.y) << 16);
}

__global__ __launch_bounds__(256) void gate_kernel(
    const float* __restrict__ ocombf, const float* __restrict__ gbuf,
    unsigned short* __restrict__ ocombb)
{
    size_t idx = (size_t)blockIdx.x * 256 + threadIdx.x;  // < MROWS*CC
    ocombb[idx] = f2b(ocombf[idx] * gbuf[idx]);
}

// ---------------------------------------------------------------------------
extern "C" void kernel_launch(void* const* d_in, const int* in_sizes, int n_in,
                              void* d_out, int out_size, void* d_ws, size_t ws_size,
                              hipStream_t stream)
{
    const float* x  = (const float*)d_in[0];
    const float* Wq = (const float*)d_in[1];
    const float* bq = (const float*)d_in[2];
    const float* Wk = (const float*)d_in[3];
    const float* bk = (const float*)d_in[4];
    const float* Wv = (const float*)d_in[5];
    const float* bv = (const float*)d_in[6];
    const float* Wa = (const float*)d_in[7];
    const float* ba = (const float*)d_in[8];
    const float* Wb = (const float*)d_in[9];
    const float* bb = (const float*)d_in[10];
    const float* Wg = (const float*)d_in[11];
    const float* bg = (const float*)d_in[12];
    const float* Wo = (const float*)d_in[13];
    const float* bo = (const float*)d_in[14];
    float* out = (float*)d_out;

    // ---- workspace layout (floats), with aliasing:
    //  qvab aliases xb (xb dead after proj GEMM; qvab written by postproj)
    //  opart aliases Y and beyond (Y dead after postproj)
    //  ocombf (atomic fallback) aliases opart
    float* ws = (float*)d_ws;
    size_t off = 0;
    float* knorm   = ws + off; off += (size_t)MROWS * CC;        // 2.10M
    float* gbuf    = ws + off; off += (size_t)MROWS * CC;        // 2.10M
    unsigned* ocombb = (unsigned*)(ws + off); off += (size_t)MROWS * CC / 2;
    unsigned short* WcatT = (unsigned short*)(ws + off); off += (size_t)NPROJ * DIMK / 2;
    unsigned short* WoT   = (unsigned short*)(ws + off); off += (size_t)DIMK * CC / 2;
    float* biascat = ws + off; off += NPROJ;
    unsigned short* xb = (unsigned short*)(ws + off);
    float* qvab    = ws + off; off += (size_t)MROWS * DIMK / 2;  // 8.39M (both)
    float* Y       = ws + off;
    size_t opart_off = off;
    off += (size_t)MROWS * YSTR;                                  // Y end
    float* ocombf  = ws + opart_off;
    unsigned* opart = (unsigned*)(ws + opart_off);
    size_t opart_end = opart_off + (size_t)NG * MROWS * 64;
    size_t need_big = (opart_end > off ? opart_end : off) * sizeof(float);
    bool big = ws_size >= need_big;

    hipLaunchKernelGGL(cast_x_kernel, dim3((size_t)MROWS * DIMK / 8 / 256), dim3(256), 0, stream,
                       x, xb);
    hipLaunchKernelGGL(pack_wt, dim3(NPROJ * DIMK / 256), dim3(256), 0, stream,
                       Wq, Wk, Wv, Wg, Wa, Wb, WcatT);
    hipLaunchKernelGGL(pack_bias, dim3(1), dim3(NPROJ), 0, stream,
                       bq, bk, bv, bg, ba, bb, biascat);
    hipLaunchKernelGGL(cast_wot, dim3(DIMK * CC / 256), dim3(256), 0, stream,
                       Wo, WoT);
    // projection GEMM: Y[16384][576] = xb @ WcatT^T + biascat
    hipLaunchKernelGGL(gemm_bt_bf16, dim3(NPROJ / 64, MROWS / 128), dim3(256), 0, stream,
                       xb, WcatT, biascat, Y, MROWS, NPROJ, DIMK);
    hipLaunchKernelGGL(postproj_kernel, dim3(MROWS), dim3(64), 0, stream,
                       Y, knorm, gbuf, (float4*)qvab);
    if (big) {
        hipLaunchKernelGGL((scan_kernel<false>), dim3(MB * NG), dim3(128), 0, stream,
                           knorm, (const float4*)qvab, (void*)opart);
        hipLaunchKernelGGL(combine_kernel, dim3(MROWS * 64 / 256), dim3(256), 0, stream,
                           opart, gbuf, ocombb);
    } else {
        (void)hipMemsetAsync(ocombf, 0, (size_t)MROWS * CC * sizeof(float), stream);
        hipLaunchKernelGGL((scan_kernel<true>), dim3(MB * NG), dim3(128), 0, stream,
                           knorm, (const float4*)qvab, (void*)ocombf);
        hipLaunchKernelGGL(gate_kernel, dim3(MROWS * CC / 256), dim3(256), 0, stream,
                           ocombf, gbuf, (unsigned short*)ocombb);
    }
    // output GEMM: out[16384][1024] = ocombb @ WoT^T + bo
    hipLaunchKernelGGL(gemm_bt_bf16, dim3(DIMK / 64, MROWS / 128), dim3(256), 0, stream,
                       (const unsigned short*)ocombb, WoT, bo, out, MROWS, DIMK, CC);
}